// Round 16
// baseline (1686.915 us; speedup 1.0000x reference)
//
#include <hip/hip_runtime.h>

#define NN 100000
#define NE 3200000
#define F 128
#define NG 64
#define NC 8
#define EPSF 1e-5f

#define AGG_BLOCKS 25000 // ceil(100000/4)
#define LDSTRIDE 136     // bf16 elems per LDS row (272B)
#define BN_BLOCKS 1024

#define NBK 256          // dst buckets
#define BNODES 391       // nodes per bucket (ceil(100000/256))
#define BCAP 14336       // entries per bucket (mean 12500, +16 sigma)
#define CHUNK 4096       // edges per bucket block
#define P1_BLOCKS ((NE + CHUNK - 1) / CHUNK)  // 782

typedef __attribute__((ext_vector_type(8))) short bf16x8;
typedef __attribute__((ext_vector_type(4))) float f32x4;
typedef _Float16 f16x2 __attribute__((ext_vector_type(2)));

union U32H2 { unsigned int u; f16x2 h; };
__device__ __forceinline__ f16x2 asH2(unsigned int u) { U32H2 c; c.u = u; return c.h; }
__device__ __forceinline__ unsigned int asU32(f16x2 h) { U32H2 c; c.h = h; return c.u; }

__device__ __forceinline__ unsigned short f2bf(float f) {
    unsigned int u = __float_as_uint(f);
    u = u + 0x7FFFu + ((u >> 16) & 1u);
    return (unsigned short)(u >> 16);
}
__device__ __forceinline__ unsigned short f2h_bits(float f) {
    union { _Float16 h; unsigned short u; } c;
    c.h = (_Float16)f;
    return c.u;
}

// ============ Kernel A: bn_partial (blocks 0..1023)  ||  bucket (blocks 1024..1805) ============
__global__ __launch_bounds__(256) void bn_bucket_k(const float* __restrict__ x,
                                                   float* __restrict__ part, int n, int rpb,
                                                   const int* __restrict__ ei,
                                                   int* __restrict__ bcur,
                                                   unsigned int* __restrict__ bbuf) {
    __shared__ float shf[512];
    __shared__ int cntl[NBK];
    __shared__ int basel[NBK];
    __shared__ int gbase[NBK];
    __shared__ unsigned int ent[CHUNK];   // 16 KB
    __shared__ unsigned char bid[CHUNK];  // 4 KB
    int tid = threadIdx.x;
    if (blockIdx.x < BN_BLOCKS) {
        int col = tid & 127, half = tid >> 7;
        int r0 = blockIdx.x * rpb, r1 = min(n, r0 + rpb);
        float s = 0.f, ss = 0.f;
        for (int r = r0 + half; r < r1; r += 2) {
            float v = x[(size_t)r * F + col];
            s += v; ss += v * v;
        }
        shf[tid] = s; shf[256 + tid] = ss;
        __syncthreads();
        if (half == 0) {
            part[blockIdx.x * 256 + col]       = shf[col] + shf[col + 128];
            part[blockIdx.x * 256 + 128 + col] = shf[256 + col] + shf[256 + col + 128];
        }
        return;
    }
    int e0 = (blockIdx.x - BN_BLOCKS) * CHUNK;
    int ecnt = min(NE - e0, CHUNK);
    cntl[tid] = 0;
    __syncthreads();
    int myr[16], myc[16], myl[16];
    #pragma unroll
    for (int k = 0; k < 16; ++k) {
        int i = tid + k * 256;
        if (i < ecnt) {
            int r = ei[e0 + i];
            int c = ei[NE + e0 + i];
            myr[k] = r; myc[k] = c;
            myl[k] = atomicAdd(&cntl[(unsigned)c / BNODES], 1);
        } else { myr[k] = -1; myc[k] = 0; myl[k] = 0; }
    }
    __syncthreads();
    int myv = cntl[tid];
    basel[tid] = myv;
    __syncthreads();
    for (int o = 1; o < 256; o <<= 1) {
        int t = (tid >= o) ? basel[tid - o] : 0;
        __syncthreads();
        basel[tid] += t;
        __syncthreads();
    }
    basel[tid] -= myv;                       // exclusive base within chunk
    gbase[tid] = atomicAdd(&bcur[tid], myv); // reserve global range
    __syncthreads();
    #pragma unroll
    for (int k = 0; k < 16; ++k) {
        if (myr[k] >= 0) {
            int b = (unsigned)myc[k] / BNODES;
            int s = basel[b] + myl[k];
            ent[s] = ((unsigned)myr[k] << 9) | (unsigned)(myc[k] - b * BNODES);
            bid[s] = (unsigned char)b;
        }
    }
    __syncthreads();
    for (int s = tid; s < ecnt; s += 256) {
        unsigned int v = ent[s];
        int b = bid[s];
        int idx = s - basel[b] + gbase[b];
        if (idx < BCAP) bbuf[(size_t)b * BCAP + idx] = v;
    }
}

// ============ Kernel B: bn_finalize (0..127) || bbase (128) || gsum zero (129) ============
__global__ void finalize_both_k(const float* __restrict__ part,
                                const float* __restrict__ bnw, const float* __restrict__ bnb,
                                float* __restrict__ scale, float* __restrict__ shift, int n,
                                const int* __restrict__ bcur, int* __restrict__ bbase,
                                int* __restrict__ offs, float* __restrict__ gsum) {
    int tid = threadIdx.x;
    if (blockIdx.x < 128) {
        int col = blockIdx.x;
        float s = 0.f, ss = 0.f;
        #pragma unroll
        for (int i = 0; i < 4; ++i) {
            int b = tid + i * 256;
            s  += part[b * 256 + col];
            ss += part[b * 256 + 128 + col];
        }
        __shared__ float shs[256], shss[256];
        shs[tid] = s; shss[tid] = ss;
        __syncthreads();
        for (int o = 128; o > 0; o >>= 1) {
            if (tid < o) { shs[tid] += shs[tid + o]; shss[tid] += shss[tid + o]; }
            __syncthreads();
        }
        if (tid == 0) {
            float mu  = shs[0] / (float)n;
            float var = shss[0] / (float)n - mu * mu;
            float rstd = rsqrtf(var + EPSF);
            float sc = bnw[col] * rstd;
            scale[col] = sc;
            shift[col] = bnb[col] - mu * sc;
        }
        return;
    }
    if (blockIdx.x == 129) {
        for (int i = tid; i < NG * F; i += 256) gsum[i] = 0.f;
        return;
    }
    __shared__ int s[256];
    int v = bcur[tid];
    s[tid] = v;
    __syncthreads();
    for (int o = 1; o < 256; o <<= 1) {
        int t = (tid >= o) ? s[tid - o] : 0;
        __syncthreads();
        s[tid] += t;
        __syncthreads();
    }
    bbase[tid] = s[tid] - v;
    if (tid == 255) offs[NN] = s[255];
}

// ============ Kernel C: prep (blocks 0..191)  ||  csr (blocks 192..447) ============
__global__ void prep_csr_k(const float* __restrict__ W1, const float* __restrict__ scale,
                           const float* __restrict__ shift,
                           unsigned short* __restrict__ WpT, float* __restrict__ S,
                           const unsigned int* __restrict__ bbuf, const int* __restrict__ bcur,
                           const int* __restrict__ bbase,
                           int* __restrict__ offs, float* __restrict__ dinv,
                           int* __restrict__ srow) {
    int tid = threadIdx.x;
    if (blockIdx.x < 64) {
        int idx = blockIdx.x * 256 + tid;  // idx = k*128 + j
        int k = idx >> 7, j = idx & 127;
        WpT[j * F + k] = f2bf(scale[k] * W1[idx]);
        return;
    }
    if (blockIdx.x < 192) {
        int j = blockIdx.x - 64;
        __shared__ float sh[256];
        sh[tid] = (tid < 128) ? shift[tid] * W1[tid * F + j] : 0.f;
        __syncthreads();
        for (int o = 128; o > 0; o >>= 1) {
            if (tid < o) sh[tid] += sh[tid + o];
            __syncthreads();
        }
        if (tid == 0) S[j] = sh[0];
        return;
    }
    int b = blockIdx.x - 192;
    __shared__ int h0[512], hA[512], hB[512];
    h0[tid] = 0; h0[tid + 256] = 0;
    __syncthreads();
    int m = min(bcur[b], BCAP);
    for (int i = tid; i < m; i += 256)
        atomicAdd(&h0[bbuf[(size_t)b * BCAP + i] & 511u], 1);
    __syncthreads();
    hA[tid] = h0[tid]; hA[tid + 256] = h0[tid + 256];
    __syncthreads();
    int* src = hA; int* dst = hB;
    for (int o = 1; o < 512; o <<= 1) {
        int i0 = tid, i1 = tid + 256;
        dst[i0] = src[i0] + ((i0 >= o) ? src[i0 - o] : 0);
        dst[i1] = src[i1] + ((i1 >= o) ? src[i1 - o] : 0);
        __syncthreads();
        int* tmp = src; src = dst; dst = tmp;
    }
    int nbase = b * BNODES;
    int base = bbase[b];
    int lim = min(BNODES, NN - nbase);
    for (int i = tid; i < lim; i += 256) {
        int d = h0[i];
        offs[nbase + i] = base + src[i] - d;   // exclusive scan
        dinv[nbase + i] = rsqrtf((float)d + 1.0f);
    }
    dst[tid] = src[tid] - h0[tid];
    dst[tid + 256] = src[tid + 256] - h0[tid + 256];
    __syncthreads();
    for (int i = tid; i < m; i += 256) {
        unsigned int v = bbuf[(size_t)b * BCAP + i];
        int dstl = (int)(v & 511u);
        int pos = base + atomicAdd(&dst[dstl], 1);
        srow[pos] = (int)(v >> 9);
    }
}

// ---------------- GEMM: hf[r][j] = f16( (x[r]@W' + S)[j] * dinv[r] )  (MFMA bf16, LDS-staged W) ----------------
__global__ __launch_bounds__(256) void gemm_k(const float* __restrict__ x,
                                              const unsigned short* __restrict__ WpT,
                                              const float* __restrict__ S,
                                              const float* __restrict__ dinv,
                                              unsigned short* __restrict__ hf, int n) {
    __shared__ unsigned short wt[128 * LDSTRIDE];
    __shared__ unsigned short xt[64 * LDSTRIDE];
    int tid = threadIdx.x;
    int row0 = blockIdx.x * 64;
    for (int i = tid; i < 2048; i += 256) {
        int r = i >> 4, c = (i & 15) * 8;
        uint4 v = *(const uint4*)&WpT[r * F + c];
        *(uint4*)&wt[r * LDSTRIDE + c] = v;
    }
    for (int i = tid; i < 2048; i += 256) {
        int r = i >> 5, c = (i & 31) * 4;
        float4 v = make_float4(0.f, 0.f, 0.f, 0.f);
        if (row0 + r < n) v = *(const float4*)&x[(size_t)(row0 + r) * F + c];
        unsigned int p0 = (unsigned int)f2bf(v.x) | ((unsigned int)f2bf(v.y) << 16);
        unsigned int p1 = (unsigned int)f2bf(v.z) | ((unsigned int)f2bf(v.w) << 16);
        *(uint2*)&xt[r * LDSTRIDE + c] = make_uint2(p0, p1);
    }
    __syncthreads();
    int wv = tid >> 6, lane = tid & 63;
    int lm = lane & 15, lk = lane >> 4;
    bf16x8 afrag[4];
    #pragma unroll
    for (int kk = 0; kk < 4; ++kk)
        afrag[kk] = *(bf16x8*)&xt[(wv * 16 + lm) * LDSTRIDE + kk * 32 + lk * 8];
    float dv[4];
    #pragma unroll
    for (int j = 0; j < 4; ++j) {
        int r = row0 + wv * 16 + lk * 4 + j;
        dv[j] = (r < n) ? dinv[r] : 1.0f;
    }
    #pragma unroll
    for (int nt = 0; nt < 8; ++nt) {
        float sv = S[nt * 16 + lm];
        f32x4 acc = {sv, sv, sv, sv};
        #pragma unroll
        for (int kk = 0; kk < 4; ++kk) {
            bf16x8 b = *(bf16x8*)&wt[(nt * 16 + lm) * LDSTRIDE + kk * 32 + lk * 8];
            acc = __builtin_amdgcn_mfma_f32_16x16x32_bf16(afrag[kk], b, acc, 0, 0, 0);
        }
        #pragma unroll
        for (int j = 0; j < 4; ++j) {
            int r = row0 + wv * 16 + lk * 4 + j;
            if (r < n) hf[(size_t)r * F + nt * 16 + lm] = f2h_bits(acc[j] * dv[j]);
        }
    }
}

// ---------------- aggregation + fused pooling: wave per node, fp16 pk adds; gsum atomics ----------------
__global__ __launch_bounds__(256) void agg_k(const uint4* __restrict__ hb4,
                                             const int* __restrict__ srow,
                                             const int* __restrict__ offs,
                                             const float* __restrict__ dinv,
                                             const float* __restrict__ bias,
                                             const int* __restrict__ batch,
                                             float* __restrict__ gsum,
                                             float* __restrict__ lnpart, int n) {
    int lane = threadIdx.x & 63, wv = threadIdx.x >> 6;
    int node = blockIdx.x * 4 + wv;
    int cg = lane & 15;    // col group: cols 8*cg .. 8*cg+7
    int sub = lane >> 4;   // edge slot within quad
    float s_part = 0.f, ss_part = 0.f;
    if (node < n) {
        int st = offs[node], en = offs[node + 1];
        float di = dinv[node];
        f16x2 a0 = {0.f16, 0.f16}, a1 = a0, a2 = a0, a3 = a0;
        if (sub == 0) {
            uint4 qs = hb4[(size_t)node * 16 + cg];  // self row
            a0 += asH2(qs.x); a1 += asH2(qs.y); a2 += asH2(qs.z); a3 += asH2(qs.w);
        }
        const uint4 qz = make_uint4(0u, 0u, 0u, 0u);
        for (int base = st; base < en; base += 64) {
            int m = en - base; if (m > 64) m = 64;
            int sv = (lane < m) ? srow[base + lane] : 0;
            int nq = (m + 3) >> 2;
            int k = 0;
            for (; k + 4 <= nq; k += 4) {   // 4 loads in flight per lane
                int i0 = 4 * k + sub, i1 = i0 + 4, i2 = i0 + 8, i3 = i0 + 12;
                int sr0 = __shfl(sv, i0), sr1 = __shfl(sv, i1);
                int sr2 = __shfl(sv, i2), sr3 = __shfl(sv, i3);
                bool v0 = i0 < m, v1 = i1 < m, v2 = i2 < m, v3 = i3 < m;
                uint4 q0 = hb4[(size_t)(v0 ? sr0 : node) * 16 + cg];
                uint4 q1 = hb4[(size_t)(v1 ? sr1 : node) * 16 + cg];
                uint4 q2 = hb4[(size_t)(v2 ? sr2 : node) * 16 + cg];
                uint4 q3 = hb4[(size_t)(v3 ? sr3 : node) * 16 + cg];
                if (!v0) q0 = qz;
                if (!v1) q1 = qz;
                if (!v2) q2 = qz;
                if (!v3) q3 = qz;
                a0 += asH2(q0.x); a1 += asH2(q0.y); a2 += asH2(q0.z); a3 += asH2(q0.w);
                a0 += asH2(q1.x); a1 += asH2(q1.y); a2 += asH2(q1.z); a3 += asH2(q1.w);
                a0 += asH2(q2.x); a1 += asH2(q2.y); a2 += asH2(q2.z); a3 += asH2(q2.w);
                a0 += asH2(q3.x); a1 += asH2(q3.y); a2 += asH2(q3.z); a3 += asH2(q3.w);
            }
            for (; k < nq; ++k) {
                int i0 = 4 * k + sub;
                int sr0 = __shfl(sv, i0);
                bool v0 = i0 < m;
                uint4 q0 = hb4[(size_t)(v0 ? sr0 : node) * 16 + cg];
                if (!v0) q0 = qz;
                a0 += asH2(q0.x); a1 += asH2(q0.y); a2 += asH2(q0.z); a3 += asH2(q0.w);
            }
        }
        // cross-sub reduction in packed fp16
        a0 += asH2((unsigned int)__shfl_xor((int)asU32(a0), 16));
        a1 += asH2((unsigned int)__shfl_xor((int)asU32(a1), 16));
        a2 += asH2((unsigned int)__shfl_xor((int)asU32(a2), 16));
        a3 += asH2((unsigned int)__shfl_xor((int)asU32(a3), 16));
        a0 += asH2((unsigned int)__shfl_xor((int)asU32(a0), 32));
        a1 += asH2((unsigned int)__shfl_xor((int)asU32(a1), 32));
        a2 += asH2((unsigned int)__shfl_xor((int)asU32(a2), 32));
        a3 += asH2((unsigned int)__shfl_xor((int)asU32(a3), 32));
        float acc[8] = {(float)a0[0], (float)a0[1], (float)a1[0], (float)a1[1],
                        (float)a2[0], (float)a2[1], (float)a3[0], (float)a3[1]};
        float4 b0 = *(const float4*)&bias[cg * 8];
        float4 b1 = *(const float4*)&bias[cg * 8 + 4];
        float bv[8] = {b0.x, b0.y, b0.z, b0.w, b1.x, b1.y, b1.z, b1.w};
        float r[8];
        #pragma unroll
        for (int j = 0; j < 8; ++j) r[j] = fmaxf(fmaf(acc[j], di, bv[j]), 0.f);
        if (sub == 0) {
            int g = batch[node];
            float* gs = &gsum[g * F + cg * 8];
            #pragma unroll
            for (int j = 0; j < 8; ++j) {
                atomicAdd(&gs[j], r[j]);
                s_part += r[j];
                ss_part += r[j] * r[j];
            }
        }
    }
    __shared__ float sh[512];
    sh[threadIdx.x] = s_part; sh[256 + threadIdx.x] = ss_part;
    __syncthreads();
    for (int o = 128; o > 0; o >>= 1) {
        if (threadIdx.x < o) {
            sh[threadIdx.x] += sh[threadIdx.x + o];
            sh[256 + threadIdx.x] += sh[256 + threadIdx.x + o];
        }
        __syncthreads();
    }
    if (threadIdx.x == 0) {
        lnpart[blockIdx.x * 2]     = sh[0];
        lnpart[blockIdx.x * 2 + 1] = sh[256];
    }
}

// ---------------- pool stage 2: LN-stat reduce (redundant per block) + mean + affine + linear ----------------
__global__ void pool2_k(const float* __restrict__ gsum, const int* __restrict__ batch,
                        const float* __restrict__ lnpart, int nb,
                        const float* __restrict__ lnw, const float* __restrict__ lnb,
                        const float* __restrict__ linW, const float* __restrict__ linb,
                        float* __restrict__ out, int n) {
    int g = blockIdx.x, tid = threadIdx.x;
    __shared__ double shd[512];
    __shared__ float lnmu, lnrs;
    double s = 0.0, ss = 0.0;
    for (int i = tid; i < nb; i += 256) {
        s  += (double)lnpart[2 * i];
        ss += (double)lnpart[2 * i + 1];
    }
    shd[tid] = s; shd[256 + tid] = ss;
    __syncthreads();
    for (int o = 128; o > 0; o >>= 1) {
        if (tid < o) { shd[tid] += shd[tid + o]; shd[256 + tid] += shd[256 + tid + o]; }
        __syncthreads();
    }
    __shared__ int bounds[2];
    if (tid == 0) {
        double cnt = (double)NN * (double)F;
        double mu = shd[0] / cnt;
        double var = shd[256] / cnt - mu * mu;
        lnmu = (float)mu;
        lnrs = (float)(1.0 / sqrt(var + (double)EPSF));
    }
    if (tid < 2) {
        int target = g + tid;
        int lo = 0, hi = n;
        while (lo < hi) {
            int mid = (lo + hi) >> 1;
            if (batch[mid] < target) lo = mid + 1; else hi = mid;
        }
        bounds[tid] = lo;
    }
    __syncthreads();
    int cg = bounds[1] - bounds[0];
    __shared__ float vals[128];
    if (tid < 128) {
        float v = 0.f;
        if (cg > 0) {
            float m = gsum[g * F + tid] / (float)cg;
            v = (m - lnmu) * lnrs * lnw[tid] + lnb[tid];
        }
        vals[tid] = v;
    }
    __syncthreads();
    if (tid < NC) {
        float o = linb[tid];
        for (int k = 0; k < F; ++k) o = fmaf(vals[k], linW[tid * F + k], o);
        out[g * NC + tid] = o;
    }
}

extern "C" void kernel_launch(void* const* d_in, const int* in_sizes, int n_in,
                              void* d_out, int out_size, void* d_ws, size_t ws_size,
                              hipStream_t stream) {
    const float* x     = (const float*)d_in[0];
    const int*   ei    = (const int*)d_in[1];
    const int*   batch = (const int*)d_in[2];
    const float* bnw   = (const float*)d_in[3];
    const float* bnb   = (const float*)d_in[4];
    const float* W1    = (const float*)d_in[5];
    const float* cbias = (const float*)d_in[6];
    const float* lnw   = (const float*)d_in[7];
    const float* lnb   = (const float*)d_in[8];
    const float* linW  = (const float*)d_in[9];
    const float* linb  = (const float*)d_in[10];
    float* out = (float*)d_out;

    char* w = (char*)d_ws;
    size_t used = 0;
    auto alloc = [&](size_t bytes) {
        char* p = w;
        size_t pad = (bytes + 255) & ~(size_t)255;
        w += pad;
        used += pad;
        return p;
    };
    // region A: bucket buffer (phase 1-2) overlaid with hf (gemm onward)
    size_t bucket_bytes = (size_t)NBK * BCAP * 4;          // 14.7 MB
    size_t hf_bytes     = (size_t)NN * F * 2;              // 25.6 MB
    char* regionA = (char*)alloc(bucket_bytes > hf_bytes ? bucket_bytes : hf_bytes);
    unsigned int*   bbuf = (unsigned int*)regionA;
    unsigned short* hf   = (unsigned short*)regionA;

    int*   srow    = (int*)alloc((size_t)NE * 4);
    int*   offs    = (int*)alloc((size_t)(NN + 1) * 4);
    float* dinv    = (float*)alloc((size_t)NN * 4);
    int*   bcur    = (int*)alloc(NBK * 4);
    int*   bbase   = (int*)alloc(NBK * 4);
    float* bnpart  = (float*)alloc((size_t)BN_BLOCKS * 256 * 4);
    float* scale   = (float*)alloc(512);
    float* shift   = (float*)alloc(512);
    unsigned short* WpT = (unsigned short*)alloc(128 * 128 * 2);
    float* Svec    = (float*)alloc(512);
    float* lnpart  = (float*)alloc((size_t)AGG_BLOCKS * 2 * 4);
    float* gsum    = (float*)alloc((size_t)NG * F * 4);

    if (used > ws_size) {  // defensive: clean fail instead of wild writes
        hipMemsetAsync(d_out, 0, (size_t)out_size * 4, stream);
        return;
    }

    hipMemsetAsync(bcur, 0, NBK * 4, stream);

    int rpb = (NN + BN_BLOCKS - 1) / BN_BLOCKS;  // 98
    bn_bucket_k<<<BN_BLOCKS + P1_BLOCKS, 256, 0, stream>>>(x, bnpart, NN, rpb, ei, bcur, bbuf);
    finalize_both_k<<<130, 256, 0, stream>>>(bnpart, bnw, bnb, scale, shift, NN,
                                             bcur, bbase, offs, gsum);
    prep_csr_k<<<448, 256, 0, stream>>>(W1, scale, shift, WpT, Svec,
                                        bbuf, bcur, bbase, offs, dinv, srow);

    gemm_k<<<(NN + 63) / 64, 256, 0, stream>>>(x, WpT, Svec, dinv, hf, NN);  // overlays bbuf
    agg_k<<<AGG_BLOCKS, 256, 0, stream>>>((const uint4*)hf, srow, offs, dinv,
                                          cbias, batch, gsum, lnpart, NN);
    pool2_k<<<NG, 256, 0, stream>>>(gsum, batch, lnpart, AGG_BLOCKS,
                                    lnw, lnb, linW, linb, out, NN);
}

// Round 17
// 265.988 us; speedup vs baseline: 6.3421x; 6.3421x over previous
//
#include <hip/hip_runtime.h>

#define NN 100000
#define NE 3200000
#define F 128
#define NG 64
#define NC 8
#define EPSF 1e-5f

#define AGG_BLOCKS 25000 // ceil(100000/4)
#define LDSTRIDE 136     // bf16 elems per LDS row (272B)
#define BN_BLOCKS 1024

#define NBK 256          // dst buckets
#define BNODES 391       // nodes per bucket (ceil(100000/256))
#define BCAP 14336       // entries per bucket (mean 12500, +16 sigma)
#define CHUNK 4096       // edges per bucket block
#define P1_BLOCKS ((NE + CHUNK - 1) / CHUNK)  // 782

typedef __attribute__((ext_vector_type(8))) short bf16x8;
typedef __attribute__((ext_vector_type(4))) float f32x4;
typedef _Float16 f16x2 __attribute__((ext_vector_type(2)));

union U32H2 { unsigned int u; f16x2 h; };
__device__ __forceinline__ f16x2 asH2(unsigned int u) { U32H2 c; c.u = u; return c.h; }
__device__ __forceinline__ unsigned int asU32(f16x2 h) { U32H2 c; c.h = h; return c.u; }

__device__ __forceinline__ unsigned short f2bf(float f) {
    unsigned int u = __float_as_uint(f);
    u = u + 0x7FFFu + ((u >> 16) & 1u);
    return (unsigned short)(u >> 16);
}
__device__ __forceinline__ unsigned short f2h_bits(float f) {
    union { _Float16 h; unsigned short u; } c;
    c.h = (_Float16)f;
    return c.u;
}

// ============ Kernel A: bn_partial (blocks 0..1023)  ||  bucket (blocks 1024..1805) ============
__global__ __launch_bounds__(256) void bn_bucket_k(const float* __restrict__ x,
                                                   float* __restrict__ part, int n, int rpb,
                                                   const int* __restrict__ ei,
                                                   int* __restrict__ bcur,
                                                   unsigned int* __restrict__ bbuf) {
    __shared__ float shf[512];
    __shared__ int cntl[NBK];
    __shared__ int basel[NBK];
    __shared__ int gbase[NBK];
    __shared__ unsigned int ent[CHUNK];   // 16 KB
    __shared__ unsigned char bid[CHUNK];  // 4 KB
    int tid = threadIdx.x;
    if (blockIdx.x < BN_BLOCKS) {
        int col = tid & 127, half = tid >> 7;
        int r0 = blockIdx.x * rpb, r1 = min(n, r0 + rpb);
        float s = 0.f, ss = 0.f;
        for (int r = r0 + half; r < r1; r += 2) {
            float v = x[(size_t)r * F + col];
            s += v; ss += v * v;
        }
        shf[tid] = s; shf[256 + tid] = ss;
        __syncthreads();
        if (half == 0) {
            part[blockIdx.x * 256 + col]       = shf[col] + shf[col + 128];
            part[blockIdx.x * 256 + 128 + col] = shf[256 + col] + shf[256 + col + 128];
        }
        return;
    }
    int e0 = (blockIdx.x - BN_BLOCKS) * CHUNK;
    int ecnt = min(NE - e0, CHUNK);
    cntl[tid] = 0;
    __syncthreads();
    int myr[16], myc[16], myl[16];
    #pragma unroll
    for (int k = 0; k < 16; ++k) {
        int i = tid + k * 256;
        if (i < ecnt) {
            int r = ei[e0 + i];
            int c = ei[NE + e0 + i];
            myr[k] = r; myc[k] = c;
            myl[k] = atomicAdd(&cntl[(unsigned)c / BNODES], 1);
        } else { myr[k] = -1; myc[k] = 0; myl[k] = 0; }
    }
    __syncthreads();
    int myv = cntl[tid];
    basel[tid] = myv;
    __syncthreads();
    for (int o = 1; o < 256; o <<= 1) {
        int t = (tid >= o) ? basel[tid - o] : 0;
        __syncthreads();
        basel[tid] += t;
        __syncthreads();
    }
    basel[tid] -= myv;                       // exclusive base within chunk
    gbase[tid] = atomicAdd(&bcur[tid], myv); // reserve global range
    __syncthreads();
    #pragma unroll
    for (int k = 0; k < 16; ++k) {
        if (myr[k] >= 0) {
            int b = (unsigned)myc[k] / BNODES;
            int s = basel[b] + myl[k];
            ent[s] = ((unsigned)myr[k] << 9) | (unsigned)(myc[k] - b * BNODES);
            bid[s] = (unsigned char)b;
        }
    }
    __syncthreads();
    for (int s = tid; s < ecnt; s += 256) {
        unsigned int v = ent[s];
        int b = bid[s];
        int idx = s - basel[b] + gbase[b];
        if (idx < BCAP) bbuf[(size_t)b * BCAP + idx] = v;
    }
}

// ============ Kernel B: bn_finalize (0..127) || bbase (128) || gsum zero (129) ============
__global__ void finalize_both_k(const float* __restrict__ part,
                                const float* __restrict__ bnw, const float* __restrict__ bnb,
                                float* __restrict__ scale, float* __restrict__ shift, int n,
                                const int* __restrict__ bcur, int* __restrict__ bbase,
                                int* __restrict__ offs, float* __restrict__ gsum) {
    int tid = threadIdx.x;
    if (blockIdx.x < 128) {
        int col = blockIdx.x;
        float s = 0.f, ss = 0.f;
        #pragma unroll
        for (int i = 0; i < 4; ++i) {
            int b = tid + i * 256;
            s  += part[b * 256 + col];
            ss += part[b * 256 + 128 + col];
        }
        __shared__ float shs[256], shss[256];
        shs[tid] = s; shss[tid] = ss;
        __syncthreads();
        for (int o = 128; o > 0; o >>= 1) {
            if (tid < o) { shs[tid] += shs[tid + o]; shss[tid] += shss[tid + o]; }
            __syncthreads();
        }
        if (tid == 0) {
            float mu  = shs[0] / (float)n;
            float var = shss[0] / (float)n - mu * mu;
            float rstd = rsqrtf(var + EPSF);
            float sc = bnw[col] * rstd;
            scale[col] = sc;
            shift[col] = bnb[col] - mu * sc;
        }
        return;
    }
    if (blockIdx.x == 129) {
        for (int i = tid; i < NG * F; i += 256) gsum[i] = 0.f;
        return;
    }
    __shared__ int s[256];
    int v = bcur[tid];
    s[tid] = v;
    __syncthreads();
    for (int o = 1; o < 256; o <<= 1) {
        int t = (tid >= o) ? s[tid - o] : 0;
        __syncthreads();
        s[tid] += t;
        __syncthreads();
    }
    bbase[tid] = s[tid] - v;
    if (tid == 255) offs[NN] = s[255];
}

// ============ Kernel C: prep (blocks 0..191)  ||  csr (blocks 192..447) ============
__global__ void prep_csr_k(const float* __restrict__ W1, const float* __restrict__ scale,
                           const float* __restrict__ shift,
                           unsigned short* __restrict__ WpT, float* __restrict__ S,
                           const unsigned int* __restrict__ bbuf, const int* __restrict__ bcur,
                           const int* __restrict__ bbase,
                           int* __restrict__ offs, float* __restrict__ dinv,
                           int* __restrict__ srow) {
    int tid = threadIdx.x;
    if (blockIdx.x < 64) {
        int idx = blockIdx.x * 256 + tid;  // idx = k*128 + j
        int k = idx >> 7, j = idx & 127;
        WpT[j * F + k] = f2bf(scale[k] * W1[idx]);
        return;
    }
    if (blockIdx.x < 192) {
        int j = blockIdx.x - 64;
        __shared__ float sh[256];
        sh[tid] = (tid < 128) ? shift[tid] * W1[tid * F + j] : 0.f;
        __syncthreads();
        for (int o = 128; o > 0; o >>= 1) {
            if (tid < o) sh[tid] += sh[tid + o];
            __syncthreads();
        }
        if (tid == 0) S[j] = sh[0];
        return;
    }
    int b = blockIdx.x - 192;
    __shared__ int h0[512], hA[512], hB[512];
    h0[tid] = 0; h0[tid + 256] = 0;
    __syncthreads();
    int m = min(bcur[b], BCAP);
    for (int i = tid; i < m; i += 256)
        atomicAdd(&h0[bbuf[(size_t)b * BCAP + i] & 511u], 1);
    __syncthreads();
    hA[tid] = h0[tid]; hA[tid + 256] = h0[tid + 256];
    __syncthreads();
    int* src = hA; int* dst = hB;
    for (int o = 1; o < 512; o <<= 1) {
        int i0 = tid, i1 = tid + 256;
        dst[i0] = src[i0] + ((i0 >= o) ? src[i0 - o] : 0);
        dst[i1] = src[i1] + ((i1 >= o) ? src[i1 - o] : 0);
        __syncthreads();
        int* tmp = src; src = dst; dst = tmp;
    }
    int nbase = b * BNODES;
    int base = bbase[b];
    int lim = min(BNODES, NN - nbase);
    for (int i = tid; i < lim; i += 256) {
        int d = h0[i];
        offs[nbase + i] = base + src[i] - d;   // exclusive scan
        dinv[nbase + i] = rsqrtf((float)d + 1.0f);
    }
    dst[tid] = src[tid] - h0[tid];
    dst[tid + 256] = src[tid + 256] - h0[tid + 256];
    __syncthreads();
    for (int i = tid; i < m; i += 256) {
        unsigned int v = bbuf[(size_t)b * BCAP + i];
        int dstl = (int)(v & 511u);
        int pos = base + atomicAdd(&dst[dstl], 1);
        srow[pos] = (int)(v >> 9);
    }
}

// ---------------- GEMM: hf[r][j] = f16( (x[r]@W' + S)[j] * dinv[r] )  (MFMA bf16, LDS-staged W) ----------------
__global__ __launch_bounds__(256) void gemm_k(const float* __restrict__ x,
                                              const unsigned short* __restrict__ WpT,
                                              const float* __restrict__ S,
                                              const float* __restrict__ dinv,
                                              unsigned short* __restrict__ hf, int n) {
    __shared__ unsigned short wt[128 * LDSTRIDE];
    __shared__ unsigned short xt[64 * LDSTRIDE];
    int tid = threadIdx.x;
    int row0 = blockIdx.x * 64;
    for (int i = tid; i < 2048; i += 256) {
        int r = i >> 4, c = (i & 15) * 8;
        uint4 v = *(const uint4*)&WpT[r * F + c];
        *(uint4*)&wt[r * LDSTRIDE + c] = v;
    }
    for (int i = tid; i < 2048; i += 256) {
        int r = i >> 5, c = (i & 31) * 4;
        float4 v = make_float4(0.f, 0.f, 0.f, 0.f);
        if (row0 + r < n) v = *(const float4*)&x[(size_t)(row0 + r) * F + c];
        unsigned int p0 = (unsigned int)f2bf(v.x) | ((unsigned int)f2bf(v.y) << 16);
        unsigned int p1 = (unsigned int)f2bf(v.z) | ((unsigned int)f2bf(v.w) << 16);
        *(uint2*)&xt[r * LDSTRIDE + c] = make_uint2(p0, p1);
    }
    __syncthreads();
    int wv = tid >> 6, lane = tid & 63;
    int lm = lane & 15, lk = lane >> 4;
    bf16x8 afrag[4];
    #pragma unroll
    for (int kk = 0; kk < 4; ++kk)
        afrag[kk] = *(bf16x8*)&xt[(wv * 16 + lm) * LDSTRIDE + kk * 32 + lk * 8];
    float dv[4];
    #pragma unroll
    for (int j = 0; j < 4; ++j) {
        int r = row0 + wv * 16 + lk * 4 + j;
        dv[j] = (r < n) ? dinv[r] : 1.0f;
    }
    #pragma unroll
    for (int nt = 0; nt < 8; ++nt) {
        float sv = S[nt * 16 + lm];
        f32x4 acc = {sv, sv, sv, sv};
        #pragma unroll
        for (int kk = 0; kk < 4; ++kk) {
            bf16x8 b = *(bf16x8*)&wt[(nt * 16 + lm) * LDSTRIDE + kk * 32 + lk * 8];
            acc = __builtin_amdgcn_mfma_f32_16x16x32_bf16(afrag[kk], b, acc, 0, 0, 0);
        }
        #pragma unroll
        for (int j = 0; j < 4; ++j) {
            int r = row0 + wv * 16 + lk * 4 + j;
            if (r < n) hf[(size_t)r * F + nt * 16 + lm] = f2h_bits(acc[j] * dv[j]);
        }
    }
}

// ---------------- aggregation: wave per node, fp16 packed adds, 4-deep load pipeline ----------------
__global__ __launch_bounds__(256) void agg_k(const uint4* __restrict__ hb4,
                                             const int* __restrict__ srow,
                                             const int* __restrict__ offs,
                                             const float* __restrict__ dinv,
                                             const float* __restrict__ bias,
                                             uint4* __restrict__ h2p4,
                                             float* __restrict__ lnpart, int n) {
    int lane = threadIdx.x & 63, wv = threadIdx.x >> 6;
    int node = blockIdx.x * 4 + wv;
    int cg = lane & 15;    // col group: cols 8*cg .. 8*cg+7
    int sub = lane >> 4;   // edge slot within quad
    float s_part = 0.f, ss_part = 0.f;
    if (node < n) {
        int st = offs[node], en = offs[node + 1];
        float di = dinv[node];
        f16x2 a0 = {0.f16, 0.f16}, a1 = a0, a2 = a0, a3 = a0;
        if (sub == 0) {
            uint4 qs = hb4[(size_t)node * 16 + cg];  // self row
            a0 += asH2(qs.x); a1 += asH2(qs.y); a2 += asH2(qs.z); a3 += asH2(qs.w);
        }
        const uint4 qz = make_uint4(0u, 0u, 0u, 0u);
        for (int base = st; base < en; base += 64) {
            int m = en - base; if (m > 64) m = 64;
            int sv = (lane < m) ? srow[base + lane] : 0;
            int nq = (m + 3) >> 2;
            int k = 0;
            for (; k + 4 <= nq; k += 4) {   // 4 loads in flight per lane
                int i0 = 4 * k + sub, i1 = i0 + 4, i2 = i0 + 8, i3 = i0 + 12;
                int sr0 = __shfl(sv, i0), sr1 = __shfl(sv, i1);
                int sr2 = __shfl(sv, i2), sr3 = __shfl(sv, i3);
                bool v0 = i0 < m, v1 = i1 < m, v2 = i2 < m, v3 = i3 < m;
                uint4 q0 = hb4[(size_t)(v0 ? sr0 : node) * 16 + cg];
                uint4 q1 = hb4[(size_t)(v1 ? sr1 : node) * 16 + cg];
                uint4 q2 = hb4[(size_t)(v2 ? sr2 : node) * 16 + cg];
                uint4 q3 = hb4[(size_t)(v3 ? sr3 : node) * 16 + cg];
                if (!v0) q0 = qz;
                if (!v1) q1 = qz;
                if (!v2) q2 = qz;
                if (!v3) q3 = qz;
                a0 += asH2(q0.x); a1 += asH2(q0.y); a2 += asH2(q0.z); a3 += asH2(q0.w);
                a0 += asH2(q1.x); a1 += asH2(q1.y); a2 += asH2(q1.z); a3 += asH2(q1.w);
                a0 += asH2(q2.x); a1 += asH2(q2.y); a2 += asH2(q2.z); a3 += asH2(q2.w);
                a0 += asH2(q3.x); a1 += asH2(q3.y); a2 += asH2(q3.z); a3 += asH2(q3.w);
            }
            for (; k < nq; ++k) {
                int i0 = 4 * k + sub;
                int sr0 = __shfl(sv, i0);
                bool v0 = i0 < m;
                uint4 q0 = hb4[(size_t)(v0 ? sr0 : node) * 16 + cg];
                if (!v0) q0 = qz;
                a0 += asH2(q0.x); a1 += asH2(q0.y); a2 += asH2(q0.z); a3 += asH2(q0.w);
            }
        }
        // cross-sub reduction in packed fp16
        a0 += asH2((unsigned int)__shfl_xor((int)asU32(a0), 16));
        a1 += asH2((unsigned int)__shfl_xor((int)asU32(a1), 16));
        a2 += asH2((unsigned int)__shfl_xor((int)asU32(a2), 16));
        a3 += asH2((unsigned int)__shfl_xor((int)asU32(a3), 16));
        a0 += asH2((unsigned int)__shfl_xor((int)asU32(a0), 32));
        a1 += asH2((unsigned int)__shfl_xor((int)asU32(a1), 32));
        a2 += asH2((unsigned int)__shfl_xor((int)asU32(a2), 32));
        a3 += asH2((unsigned int)__shfl_xor((int)asU32(a3), 32));
        float acc[8] = {(float)a0[0], (float)a0[1], (float)a1[0], (float)a1[1],
                        (float)a2[0], (float)a2[1], (float)a3[0], (float)a3[1]};
        float4 b0 = *(const float4*)&bias[cg * 8];
        float4 b1 = *(const float4*)&bias[cg * 8 + 4];
        float bv[8] = {b0.x, b0.y, b0.z, b0.w, b1.x, b1.y, b1.z, b1.w};
        float r[8];
        #pragma unroll
        for (int j = 0; j < 8; ++j) r[j] = fmaxf(fmaf(acc[j], di, bv[j]), 0.f);
        if (sub == 0) {
            uint4 p;
            p.x = asU32(f16x2{(_Float16)r[0], (_Float16)r[1]});
            p.y = asU32(f16x2{(_Float16)r[2], (_Float16)r[3]});
            p.z = asU32(f16x2{(_Float16)r[4], (_Float16)r[5]});
            p.w = asU32(f16x2{(_Float16)r[6], (_Float16)r[7]});
            h2p4[(size_t)node * 16 + cg] = p;
            #pragma unroll
            for (int j = 0; j < 8; ++j) {
                s_part += r[j];
                ss_part += r[j] * r[j];
            }
        }
    }
    __shared__ float sh[512];
    sh[threadIdx.x] = s_part; sh[256 + threadIdx.x] = ss_part;
    __syncthreads();
    for (int o = 128; o > 0; o >>= 1) {
        if (threadIdx.x < o) {
            sh[threadIdx.x] += sh[threadIdx.x + o];
            sh[256 + threadIdx.x] += sh[256 + threadIdx.x + o];
        }
        __syncthreads();
    }
    if (threadIdx.x == 0) {
        lnpart[blockIdx.x * 2]     = sh[0];
        lnpart[blockIdx.x * 2 + 1] = sh[256];
    }
}

// ---------------- pool stage 1 (fp16 h, packed pairs; run-length flush + few atomics) ----------------
__global__ void pool1_k(const unsigned int* __restrict__ h2p, const int* __restrict__ batch,
                        float* __restrict__ gsum, int n) {
    int tid = threadIdx.x, cp = tid & 63, half = tid >> 6;  // 4-way row split
    int n0 = blockIdx.x * 256, n1 = min(n, n0 + 256);
    int r = n0 + half;
    if (r >= n1) return;
    int gcur = batch[r];
    float a0 = 0.f, a1 = 0.f;
    for (; r < n1; r += 4) {
        int g = batch[r];
        f16x2 hp = asH2(h2p[(size_t)r * 64 + cp]);
        if (g != gcur) {
            atomicAdd(&gsum[gcur * F + cp * 2], a0);
            atomicAdd(&gsum[gcur * F + cp * 2 + 1], a1);
            a0 = a1 = 0.f; gcur = g;
        }
        a0 += (float)hp[0];
        a1 += (float)hp[1];
    }
    atomicAdd(&gsum[gcur * F + cp * 2], a0);
    atomicAdd(&gsum[gcur * F + cp * 2 + 1], a1);
}

// ---------------- pool stage 2: LN-stat reduce (redundant per block) + mean + affine + linear ----------------
__global__ void pool2_k(const float* __restrict__ gsum, const int* __restrict__ batch,
                        const float* __restrict__ lnpart, int nb,
                        const float* __restrict__ lnw, const float* __restrict__ lnb,
                        const float* __restrict__ linW, const float* __restrict__ linb,
                        float* __restrict__ out, int n) {
    int g = blockIdx.x, tid = threadIdx.x;
    __shared__ double shd[512];
    __shared__ float lnmu, lnrs;
    double s = 0.0, ss = 0.0;
    for (int i = tid; i < nb; i += 256) {
        s  += (double)lnpart[2 * i];
        ss += (double)lnpart[2 * i + 1];
    }
    shd[tid] = s; shd[256 + tid] = ss;
    __syncthreads();
    for (int o = 128; o > 0; o >>= 1) {
        if (tid < o) { shd[tid] += shd[tid + o]; shd[256 + tid] += shd[256 + tid + o]; }
        __syncthreads();
    }
    __shared__ int bounds[2];
    if (tid == 0) {
        double cnt = (double)NN * (double)F;
        double mu = shd[0] / cnt;
        double var = shd[256] / cnt - mu * mu;
        lnmu = (float)mu;
        lnrs = (float)(1.0 / sqrt(var + (double)EPSF));
    }
    if (tid < 2) {
        int target = g + tid;
        int lo = 0, hi = n;
        while (lo < hi) {
            int mid = (lo + hi) >> 1;
            if (batch[mid] < target) lo = mid + 1; else hi = mid;
        }
        bounds[tid] = lo;
    }
    __syncthreads();
    int cg = bounds[1] - bounds[0];
    __shared__ float vals[128];
    if (tid < 128) {
        float v = 0.f;
        if (cg > 0) {
            float m = gsum[g * F + tid] / (float)cg;
            v = (m - lnmu) * lnrs * lnw[tid] + lnb[tid];
        }
        vals[tid] = v;
    }
    __syncthreads();
    if (tid < NC) {
        float o = linb[tid];
        for (int k = 0; k < F; ++k) o = fmaf(vals[k], linW[tid * F + k], o);
        out[g * NC + tid] = o;
    }
}

extern "C" void kernel_launch(void* const* d_in, const int* in_sizes, int n_in,
                              void* d_out, int out_size, void* d_ws, size_t ws_size,
                              hipStream_t stream) {
    const float* x     = (const float*)d_in[0];
    const int*   ei    = (const int*)d_in[1];
    const int*   batch = (const int*)d_in[2];
    const float* bnw   = (const float*)d_in[3];
    const float* bnb   = (const float*)d_in[4];
    const float* W1    = (const float*)d_in[5];
    const float* cbias = (const float*)d_in[6];
    const float* lnw   = (const float*)d_in[7];
    const float* lnb   = (const float*)d_in[8];
    const float* linW  = (const float*)d_in[9];
    const float* linb  = (const float*)d_in[10];
    float* out = (float*)d_out;

    char* w = (char*)d_ws;
    size_t used = 0;
    auto alloc = [&](size_t bytes) {
        char* p = w;
        size_t pad = (bytes + 255) & ~(size_t)255;
        w += pad;
        used += pad;
        return p;
    };
    // region A: bucket buffer (phase 1-2) overlaid with hf (gemm onward)
    size_t bucket_bytes = (size_t)NBK * BCAP * 4;          // 14.7 MB
    size_t hf_bytes     = (size_t)NN * F * 2;              // 25.6 MB
    char* regionA = (char*)alloc(bucket_bytes > hf_bytes ? bucket_bytes : hf_bytes);
    unsigned int*   bbuf = (unsigned int*)regionA;
    unsigned short* hf   = (unsigned short*)regionA;

    unsigned int* h2p = (unsigned int*)alloc((size_t)NN * F * 2);  // fp16 packed pairs
    int*   srow    = (int*)alloc((size_t)NE * 4);
    int*   offs    = (int*)alloc((size_t)(NN + 1) * 4);
    float* dinv    = (float*)alloc((size_t)NN * 4);
    int*   bcur    = (int*)alloc(NBK * 4);
    int*   bbase   = (int*)alloc(NBK * 4);
    float* bnpart  = (float*)alloc((size_t)BN_BLOCKS * 256 * 4);
    float* scale   = (float*)alloc(512);
    float* shift   = (float*)alloc(512);
    unsigned short* WpT = (unsigned short*)alloc(128 * 128 * 2);
    float* Svec    = (float*)alloc(512);
    float* lnpart  = (float*)alloc((size_t)AGG_BLOCKS * 2 * 4);
    float* gsum    = (float*)alloc((size_t)NG * F * 4);

    if (used > ws_size) {  // defensive: clean fail instead of wild writes
        hipMemsetAsync(d_out, 0, (size_t)out_size * 4, stream);
        return;
    }

    hipMemsetAsync(bcur, 0, NBK * 4, stream);

    int rpb = (NN + BN_BLOCKS - 1) / BN_BLOCKS;  // 98
    bn_bucket_k<<<BN_BLOCKS + P1_BLOCKS, 256, 0, stream>>>(x, bnpart, NN, rpb, ei, bcur, bbuf);
    finalize_both_k<<<130, 256, 0, stream>>>(bnpart, bnw, bnb, scale, shift, NN,
                                             bcur, bbase, offs, gsum);
    prep_csr_k<<<448, 256, 0, stream>>>(W1, scale, shift, WpT, Svec,
                                        bbuf, bcur, bbase, offs, dinv, srow);

    gemm_k<<<(NN + 63) / 64, 256, 0, stream>>>(x, WpT, Svec, dinv, hf, NN);  // overlays bbuf
    agg_k<<<AGG_BLOCKS, 256, 0, stream>>>((const uint4*)hf, srow, offs, dinv,
                                          cbias, (uint4*)h2p, lnpart, NN);
    pool1_k<<<(NN + 255) / 256, 256, 0, stream>>>(h2p, batch, gsum, NN);
    pool2_k<<<NG, 256, 0, stream>>>(gsum, batch, lnpart, AGG_BLOCKS,
                                    lnw, lnb, linW, linb, out, NN);
}

// Round 18
// 244.520 us; speedup vs baseline: 6.8989x; 1.0878x over previous
//
#include <hip/hip_runtime.h>

#define NN 100000
#define NE 3200000
#define F 128
#define NG 64
#define NC 8
#define EPSF 1e-5f

#define AGG_BLOCKS 25000 // ceil(100000/4)
#define LDSTRIDE 136     // bf16 elems per LDS row (272B)
#define BN_BLOCKS 1024

#define NBK 256          // dst buckets
#define BNODES 391       // nodes per bucket (ceil(100000/256))
#define BCAP 14336       // entries per bucket (mean 12500, +16 sigma)
#define CHUNK 4096       // edges per bucket block
#define P1_BLOCKS ((NE + CHUNK - 1) / CHUNK)  // 782
#define GEMM_BLOCKS ((NN + 63) / 64)          // 1563

typedef __attribute__((ext_vector_type(8))) short bf16x8;
typedef __attribute__((ext_vector_type(4))) float f32x4;
typedef _Float16 f16x2 __attribute__((ext_vector_type(2)));

union U32H2 { unsigned int u; f16x2 h; };
__device__ __forceinline__ f16x2 asH2(unsigned int u) { U32H2 c; c.u = u; return c.h; }
__device__ __forceinline__ unsigned int asU32(f16x2 h) { U32H2 c; c.h = h; return c.u; }

__device__ __forceinline__ unsigned short f2bf(float f) {
    unsigned int u = __float_as_uint(f);
    u = u + 0x7FFFu + ((u >> 16) & 1u);
    return (unsigned short)(u >> 16);
}
__device__ __forceinline__ unsigned short f2h_bits(float f) {
    union { _Float16 h; unsigned short u; } c;
    c.h = (_Float16)f;
    return c.u;
}

// ============ Kernel A: bn_partial (blocks 0..1023)  ||  bucket (blocks 1024..1805) ============
__global__ __launch_bounds__(256) void bn_bucket_k(const float* __restrict__ x,
                                                   float* __restrict__ part, int n, int rpb,
                                                   const int* __restrict__ ei,
                                                   int* __restrict__ bcur,
                                                   unsigned int* __restrict__ bbuf) {
    __shared__ float shf[512];
    __shared__ int cntl[NBK];
    __shared__ int basel[NBK];
    __shared__ int gbase[NBK];
    __shared__ unsigned int ent[CHUNK];   // 16 KB
    __shared__ unsigned char bid[CHUNK];  // 4 KB
    int tid = threadIdx.x;
    if (blockIdx.x < BN_BLOCKS) {
        int col = tid & 127, half = tid >> 7;
        int r0 = blockIdx.x * rpb, r1 = min(n, r0 + rpb);
        float s = 0.f, ss = 0.f;
        for (int r = r0 + half; r < r1; r += 2) {
            float v = x[(size_t)r * F + col];
            s += v; ss += v * v;
        }
        shf[tid] = s; shf[256 + tid] = ss;
        __syncthreads();
        if (half == 0) {
            part[blockIdx.x * 256 + col]       = shf[col] + shf[col + 128];
            part[blockIdx.x * 256 + 128 + col] = shf[256 + col] + shf[256 + col + 128];
        }
        return;
    }
    int e0 = (blockIdx.x - BN_BLOCKS) * CHUNK;
    int ecnt = min(NE - e0, CHUNK);
    cntl[tid] = 0;
    __syncthreads();
    int myr[16], myc[16], myl[16];
    #pragma unroll
    for (int k = 0; k < 16; ++k) {
        int i = tid + k * 256;
        if (i < ecnt) {
            int r = ei[e0 + i];
            int c = ei[NE + e0 + i];
            myr[k] = r; myc[k] = c;
            myl[k] = atomicAdd(&cntl[(unsigned)c / BNODES], 1);
        } else { myr[k] = -1; myc[k] = 0; myl[k] = 0; }
    }
    __syncthreads();
    int myv = cntl[tid];
    basel[tid] = myv;
    __syncthreads();
    for (int o = 1; o < 256; o <<= 1) {
        int t = (tid >= o) ? basel[tid - o] : 0;
        __syncthreads();
        basel[tid] += t;
        __syncthreads();
    }
    basel[tid] -= myv;                       // exclusive base within chunk
    gbase[tid] = atomicAdd(&bcur[tid], myv); // reserve global range
    __syncthreads();
    #pragma unroll
    for (int k = 0; k < 16; ++k) {
        if (myr[k] >= 0) {
            int b = (unsigned)myc[k] / BNODES;
            int s = basel[b] + myl[k];
            ent[s] = ((unsigned)myr[k] << 9) | (unsigned)(myc[k] - b * BNODES);
            bid[s] = (unsigned char)b;
        }
    }
    __syncthreads();
    for (int s = tid; s < ecnt; s += 256) {
        unsigned int v = ent[s];
        int b = bid[s];
        int idx = s - basel[b] + gbase[b];
        if (idx < BCAP) bbuf[(size_t)b * BCAP + idx] = v;
    }
}

// ============ Kernel B: bn_finalize (0..127) || bbase (128) || gsum+lnsum zero (129) ============
__global__ void finalize_both_k(const float* __restrict__ part,
                                const float* __restrict__ bnw, const float* __restrict__ bnb,
                                float* __restrict__ scale, float* __restrict__ shift, int n,
                                const int* __restrict__ bcur, int* __restrict__ bbase,
                                int* __restrict__ offs, float* __restrict__ gsum,
                                float* __restrict__ lnsum) {
    int tid = threadIdx.x;
    if (blockIdx.x < 128) {
        int col = blockIdx.x;
        float s = 0.f, ss = 0.f;
        #pragma unroll
        for (int i = 0; i < 4; ++i) {
            int b = tid + i * 256;
            s  += part[b * 256 + col];
            ss += part[b * 256 + 128 + col];
        }
        __shared__ float shs[256], shss[256];
        shs[tid] = s; shss[tid] = ss;
        __syncthreads();
        for (int o = 128; o > 0; o >>= 1) {
            if (tid < o) { shs[tid] += shs[tid + o]; shss[tid] += shss[tid + o]; }
            __syncthreads();
        }
        if (tid == 0) {
            float mu  = shs[0] / (float)n;
            float var = shss[0] / (float)n - mu * mu;
            float rstd = rsqrtf(var + EPSF);
            float sc = bnw[col] * rstd;
            scale[col] = sc;
            shift[col] = bnb[col] - mu * sc;
        }
        return;
    }
    if (blockIdx.x == 129) {
        for (int i = tid; i < NG * F; i += 256) gsum[i] = 0.f;
        if (tid < 2) lnsum[tid] = 0.f;
        return;
    }
    __shared__ int s[256];
    int v = bcur[tid];
    s[tid] = v;
    __syncthreads();
    for (int o = 1; o < 256; o <<= 1) {
        int t = (tid >= o) ? s[tid - o] : 0;
        __syncthreads();
        s[tid] += t;
        __syncthreads();
    }
    bbase[tid] = s[tid] - v;
    if (tid == 255) offs[NN] = s[255];
}

// ============ Kernel C1: prep (blocks 0..191)  ||  histogram->offs/dinv (blocks 192..447) ============
__global__ void prep_hist_k(const float* __restrict__ W1, const float* __restrict__ scale,
                            const float* __restrict__ shift,
                            unsigned short* __restrict__ WpT, float* __restrict__ S,
                            const unsigned int* __restrict__ bbuf, const int* __restrict__ bcur,
                            const int* __restrict__ bbase,
                            int* __restrict__ offs, float* __restrict__ dinv) {
    int tid = threadIdx.x;
    if (blockIdx.x < 64) {
        int idx = blockIdx.x * 256 + tid;  // idx = k*128 + j
        int k = idx >> 7, j = idx & 127;
        WpT[j * F + k] = f2bf(scale[k] * W1[idx]);
        return;
    }
    if (blockIdx.x < 192) {
        int j = blockIdx.x - 64;
        __shared__ float sh[256];
        sh[tid] = (tid < 128) ? shift[tid] * W1[tid * F + j] : 0.f;
        __syncthreads();
        for (int o = 128; o > 0; o >>= 1) {
            if (tid < o) sh[tid] += sh[tid + o];
            __syncthreads();
        }
        if (tid == 0) S[j] = sh[0];
        return;
    }
    int b = blockIdx.x - 192;
    __shared__ int h0[512], hA[512], hB[512];
    h0[tid] = 0; h0[tid + 256] = 0;
    __syncthreads();
    int m = min(bcur[b], BCAP);
    for (int i = tid; i < m; i += 256)
        atomicAdd(&h0[bbuf[(size_t)b * BCAP + i] & 511u], 1);
    __syncthreads();
    hA[tid] = h0[tid]; hA[tid + 256] = h0[tid + 256];
    __syncthreads();
    int* src = hA; int* dst = hB;
    for (int o = 1; o < 512; o <<= 1) {
        int i0 = tid, i1 = tid + 256;
        dst[i0] = src[i0] + ((i0 >= o) ? src[i0 - o] : 0);
        dst[i1] = src[i1] + ((i1 >= o) ? src[i1 - o] : 0);
        __syncthreads();
        int* tmp = src; src = dst; dst = tmp;
    }
    int nbase = b * BNODES;
    int base = bbase[b];
    int lim = min(BNODES, NN - nbase);
    for (int i = tid; i < lim; i += 256) {
        int d = h0[i];
        offs[nbase + i] = base + src[i] - d;   // exclusive scan
        dinv[nbase + i] = rsqrtf((float)d + 1.0f);
    }
}

// ============ Kernel C2: scatter (blocks 0..255)  ||  GEMM (blocks 256..1818) ============
__global__ __launch_bounds__(256) void scatter_gemm_k(
        const unsigned int* __restrict__ bbuf, const int* __restrict__ bcur,
        const int* __restrict__ offs, int* __restrict__ srow,
        const float* __restrict__ x, const unsigned short* __restrict__ WpT,
        const float* __restrict__ S, const float* __restrict__ dinv,
        unsigned short* __restrict__ hf, int n) {
    __shared__ __align__(16) char smem[128 * LDSTRIDE * 2 + 64 * LDSTRIDE * 2];
    int tid = threadIdx.x;
    if (blockIdx.x < NBK) {
        int b = blockIdx.x;
        int* cur = (int*)smem;
        for (int i = tid; i < BNODES; i += 256) cur[i] = 0;
        __syncthreads();
        int nbase = b * BNODES;
        int m = min(bcur[b], BCAP);
        for (int i = tid; i < m; i += 256) {
            unsigned int v = bbuf[(size_t)b * BCAP + i];
            int dstl = (int)(v & 511u);
            int pos = offs[nbase + dstl] + atomicAdd(&cur[dstl], 1);
            srow[pos] = (int)(v >> 9);
        }
        return;
    }
    unsigned short* wt = (unsigned short*)smem;
    unsigned short* xt = (unsigned short*)(smem + 128 * LDSTRIDE * 2);
    int row0 = (blockIdx.x - NBK) * 64;
    for (int i = tid; i < 2048; i += 256) {
        int r = i >> 4, c = (i & 15) * 8;
        uint4 v = *(const uint4*)&WpT[r * F + c];
        *(uint4*)&wt[r * LDSTRIDE + c] = v;
    }
    for (int i = tid; i < 2048; i += 256) {
        int r = i >> 5, c = (i & 31) * 4;
        float4 v = make_float4(0.f, 0.f, 0.f, 0.f);
        if (row0 + r < n) v = *(const float4*)&x[(size_t)(row0 + r) * F + c];
        unsigned int p0 = (unsigned int)f2bf(v.x) | ((unsigned int)f2bf(v.y) << 16);
        unsigned int p1 = (unsigned int)f2bf(v.z) | ((unsigned int)f2bf(v.w) << 16);
        *(uint2*)&xt[r * LDSTRIDE + c] = make_uint2(p0, p1);
    }
    __syncthreads();
    int wv = tid >> 6, lane = tid & 63;
    int lm = lane & 15, lk = lane >> 4;
    bf16x8 afrag[4];
    #pragma unroll
    for (int kk = 0; kk < 4; ++kk)
        afrag[kk] = *(bf16x8*)&xt[(wv * 16 + lm) * LDSTRIDE + kk * 32 + lk * 8];
    float dv[4];
    #pragma unroll
    for (int j = 0; j < 4; ++j) {
        int r = row0 + wv * 16 + lk * 4 + j;
        dv[j] = (r < n) ? dinv[r] : 1.0f;
    }
    #pragma unroll
    for (int nt = 0; nt < 8; ++nt) {
        float sv = S[nt * 16 + lm];
        f32x4 acc = {sv, sv, sv, sv};
        #pragma unroll
        for (int kk = 0; kk < 4; ++kk) {
            bf16x8 b = *(bf16x8*)&wt[(nt * 16 + lm) * LDSTRIDE + kk * 32 + lk * 8];
            acc = __builtin_amdgcn_mfma_f32_16x16x32_bf16(afrag[kk], b, acc, 0, 0, 0);
        }
        #pragma unroll
        for (int j = 0; j < 4; ++j) {
            int r = row0 + wv * 16 + lk * 4 + j;
            if (r < n) hf[(size_t)r * F + nt * 16 + lm] = f2h_bits(acc[j] * dv[j]);
        }
    }
}

// ---------------- aggregation: wave per node, fp16 packed adds, 4-deep load pipeline ----------------
__global__ __launch_bounds__(256) void agg_k(const uint4* __restrict__ hb4,
                                             const int* __restrict__ srow,
                                             const int* __restrict__ offs,
                                             const float* __restrict__ dinv,
                                             const float* __restrict__ bias,
                                             uint4* __restrict__ h2p4,
                                             float* __restrict__ lnpart, int n) {
    int lane = threadIdx.x & 63, wv = threadIdx.x >> 6;
    int node = blockIdx.x * 4 + wv;
    int cg = lane & 15;    // col group: cols 8*cg .. 8*cg+7
    int sub = lane >> 4;   // edge slot within quad
    float s_part = 0.f, ss_part = 0.f;
    if (node < n) {
        int st = offs[node], en = offs[node + 1];
        float di = dinv[node];
        f16x2 a0 = {0.f16, 0.f16}, a1 = a0, a2 = a0, a3 = a0;
        if (sub == 0) {
            uint4 qs = hb4[(size_t)node * 16 + cg];  // self row
            a0 += asH2(qs.x); a1 += asH2(qs.y); a2 += asH2(qs.z); a3 += asH2(qs.w);
        }
        const uint4 qz = make_uint4(0u, 0u, 0u, 0u);
        for (int base = st; base < en; base += 64) {
            int m = en - base; if (m > 64) m = 64;
            int sv = (lane < m) ? srow[base + lane] : 0;
            int nq = (m + 3) >> 2;
            int k = 0;
            for (; k + 4 <= nq; k += 4) {   // 4 loads in flight per lane
                int i0 = 4 * k + sub, i1 = i0 + 4, i2 = i0 + 8, i3 = i0 + 12;
                int sr0 = __shfl(sv, i0), sr1 = __shfl(sv, i1);
                int sr2 = __shfl(sv, i2), sr3 = __shfl(sv, i3);
                bool v0 = i0 < m, v1 = i1 < m, v2 = i2 < m, v3 = i3 < m;
                uint4 q0 = hb4[(size_t)(v0 ? sr0 : node) * 16 + cg];
                uint4 q1 = hb4[(size_t)(v1 ? sr1 : node) * 16 + cg];
                uint4 q2 = hb4[(size_t)(v2 ? sr2 : node) * 16 + cg];
                uint4 q3 = hb4[(size_t)(v3 ? sr3 : node) * 16 + cg];
                if (!v0) q0 = qz;
                if (!v1) q1 = qz;
                if (!v2) q2 = qz;
                if (!v3) q3 = qz;
                a0 += asH2(q0.x); a1 += asH2(q0.y); a2 += asH2(q0.z); a3 += asH2(q0.w);
                a0 += asH2(q1.x); a1 += asH2(q1.y); a2 += asH2(q1.z); a3 += asH2(q1.w);
                a0 += asH2(q2.x); a1 += asH2(q2.y); a2 += asH2(q2.z); a3 += asH2(q2.w);
                a0 += asH2(q3.x); a1 += asH2(q3.y); a2 += asH2(q3.z); a3 += asH2(q3.w);
            }
            for (; k < nq; ++k) {
                int i0 = 4 * k + sub;
                int sr0 = __shfl(sv, i0);
                bool v0 = i0 < m;
                uint4 q0 = hb4[(size_t)(v0 ? sr0 : node) * 16 + cg];
                if (!v0) q0 = qz;
                a0 += asH2(q0.x); a1 += asH2(q0.y); a2 += asH2(q0.z); a3 += asH2(q0.w);
            }
        }
        // cross-sub reduction in packed fp16
        a0 += asH2((unsigned int)__shfl_xor((int)asU32(a0), 16));
        a1 += asH2((unsigned int)__shfl_xor((int)asU32(a1), 16));
        a2 += asH2((unsigned int)__shfl_xor((int)asU32(a2), 16));
        a3 += asH2((unsigned int)__shfl_xor((int)asU32(a3), 16));
        a0 += asH2((unsigned int)__shfl_xor((int)asU32(a0), 32));
        a1 += asH2((unsigned int)__shfl_xor((int)asU32(a1), 32));
        a2 += asH2((unsigned int)__shfl_xor((int)asU32(a2), 32));
        a3 += asH2((unsigned int)__shfl_xor((int)asU32(a3), 32));
        float acc[8] = {(float)a0[0], (float)a0[1], (float)a1[0], (float)a1[1],
                        (float)a2[0], (float)a2[1], (float)a3[0], (float)a3[1]};
        float4 b0 = *(const float4*)&bias[cg * 8];
        float4 b1 = *(const float4*)&bias[cg * 8 + 4];
        float bv[8] = {b0.x, b0.y, b0.z, b0.w, b1.x, b1.y, b1.z, b1.w};
        float r[8];
        #pragma unroll
        for (int j = 0; j < 8; ++j) r[j] = fmaxf(fmaf(acc[j], di, bv[j]), 0.f);
        if (sub == 0) {
            uint4 p;
            p.x = asU32(f16x2{(_Float16)r[0], (_Float16)r[1]});
            p.y = asU32(f16x2{(_Float16)r[2], (_Float16)r[3]});
            p.z = asU32(f16x2{(_Float16)r[4], (_Float16)r[5]});
            p.w = asU32(f16x2{(_Float16)r[6], (_Float16)r[7]});
            h2p4[(size_t)node * 16 + cg] = p;
            #pragma unroll
            for (int j = 0; j < 8; ++j) {
                s_part += r[j];
                ss_part += r[j] * r[j];
            }
        }
    }
    __shared__ float sh[512];
    sh[threadIdx.x] = s_part; sh[256 + threadIdx.x] = ss_part;
    __syncthreads();
    for (int o = 128; o > 0; o >>= 1) {
        if (threadIdx.x < o) {
            sh[threadIdx.x] += sh[threadIdx.x + o];
            sh[256 + threadIdx.x] += sh[256 + threadIdx.x + o];
        }
        __syncthreads();
    }
    if (threadIdx.x == 0) {
        lnpart[blockIdx.x * 2]     = sh[0];
        lnpart[blockIdx.x * 2 + 1] = sh[256];
    }
}

// ---------------- pool stage 1: lnpart slice reduce (wave 0) + gsum run-length accumulation ----------------
__global__ void pool1_k(const unsigned int* __restrict__ h2p, const int* __restrict__ batch,
                        float* __restrict__ gsum, float* __restrict__ lnsum, int n) {
    int tid = threadIdx.x;
    if (tid < 64) {   // wave 0: reduce this block's 64-pair slice of lnpart into lnsum
        int e = blockIdx.x * 64 + tid;
        float s = 0.f, ss = 0.f;
        if (e < AGG_BLOCKS) {
            const float* lp = lnsum + 2;  // lnpart passed right after lnsum (see launch)
            s  = lp[2 * e];
            ss = lp[2 * e + 1];
        }
        #pragma unroll
        for (int o = 32; o > 0; o >>= 1) {
            s  += __shfl_down(s, o);
            ss += __shfl_down(ss, o);
        }
        if (tid == 0) {
            atomicAdd(&lnsum[0], s);
            atomicAdd(&lnsum[1], ss);
        }
    }
    int cp = tid & 63, half = tid >> 6;  // 4-way row split
    int n0 = blockIdx.x * 256, n1 = min(n, n0 + 256);
    int r = n0 + half;
    if (r >= n1) return;
    int gcur = batch[r];
    float a0 = 0.f, a1 = 0.f;
    for (; r < n1; r += 4) {
        int g = batch[r];
        f16x2 hp = asH2(h2p[(size_t)r * 64 + cp]);
        if (g != gcur) {
            atomicAdd(&gsum[gcur * F + cp * 2], a0);
            atomicAdd(&gsum[gcur * F + cp * 2 + 1], a1);
            a0 = a1 = 0.f; gcur = g;
        }
        a0 += (float)hp[0];
        a1 += (float)hp[1];
    }
    atomicAdd(&gsum[gcur * F + cp * 2], a0);
    atomicAdd(&gsum[gcur * F + cp * 2 + 1], a1);
}

// ---------------- pool stage 2: mean + LN affine + linear (lnsum precomputed) ----------------
__global__ void pool2_k(const float* __restrict__ gsum, const int* __restrict__ batch,
                        const float* __restrict__ lnsum,
                        const float* __restrict__ lnw, const float* __restrict__ lnb,
                        const float* __restrict__ linW, const float* __restrict__ linb,
                        float* __restrict__ out, int n) {
    int g = blockIdx.x, tid = threadIdx.x;
    __shared__ float lnmu, lnrs;
    __shared__ int bounds[2];
    if (tid == 0) {
        float cnt = (float)NN * (float)F;
        float mu = lnsum[0] / cnt;
        float var = lnsum[1] / cnt - mu * mu;
        lnmu = mu;
        lnrs = rsqrtf(var + EPSF);
    }
    if (tid < 2) {
        int target = g + tid;
        int lo = 0, hi = n;
        while (lo < hi) {
            int mid = (lo + hi) >> 1;
            if (batch[mid] < target) lo = mid + 1; else hi = mid;
        }
        bounds[tid] = lo;
    }
    __syncthreads();
    int cg = bounds[1] - bounds[0];
    __shared__ float vals[128];
    if (tid < 128) {
        float v = 0.f;
        if (cg > 0) {
            float m = gsum[g * F + tid] / (float)cg;
            v = (m - lnmu) * lnrs * lnw[tid] + lnb[tid];
        }
        vals[tid] = v;
    }
    __syncthreads();
    if (tid < NC) {
        float o = linb[tid];
        for (int k = 0; k < F; ++k) o = fmaf(vals[k], linW[tid * F + k], o);
        out[g * NC + tid] = o;
    }
}

extern "C" void kernel_launch(void* const* d_in, const int* in_sizes, int n_in,
                              void* d_out, int out_size, void* d_ws, size_t ws_size,
                              hipStream_t stream) {
    const float* x     = (const float*)d_in[0];
    const int*   ei    = (const int*)d_in[1];
    const int*   batch = (const int*)d_in[2];
    const float* bnw   = (const float*)d_in[3];
    const float* bnb   = (const float*)d_in[4];
    const float* W1    = (const float*)d_in[5];
    const float* cbias = (const float*)d_in[6];
    const float* lnw   = (const float*)d_in[7];
    const float* lnb   = (const float*)d_in[8];
    const float* linW  = (const float*)d_in[9];
    const float* linb  = (const float*)d_in[10];
    float* out = (float*)d_out;

    char* w = (char*)d_ws;
    size_t used = 0;
    auto alloc = [&](size_t bytes) {
        char* p = w;
        size_t pad = (bytes + 255) & ~(size_t)255;
        w += pad;
        used += pad;
        return p;
    };
    // region A: bucket buffer (A/C1/C2 scatter) overlaid with h2p (agg onward; bbuf dead by then)
    size_t bucket_bytes = (size_t)NBK * BCAP * 4;          // 14.7 MB
    size_t h2p_bytes    = (size_t)NN * F * 2;              // 25.6 MB
    char* regionA = (char*)alloc(bucket_bytes > h2p_bytes ? bucket_bytes : h2p_bytes);
    unsigned int* bbuf = (unsigned int*)regionA;
    unsigned int* h2p  = (unsigned int*)regionA;

    unsigned short* hf = (unsigned short*)alloc((size_t)NN * F * 2);  // fp16 h (gemm out)
    int*   srow    = (int*)alloc((size_t)NE * 4);
    int*   offs    = (int*)alloc((size_t)(NN + 1) * 4);
    float* dinv    = (float*)alloc((size_t)NN * 4);
    int*   bcur    = (int*)alloc(NBK * 4);
    int*   bbase   = (int*)alloc(NBK * 4);
    float* bnpart  = (float*)alloc((size_t)BN_BLOCKS * 256 * 4);
    float* scale   = (float*)alloc(512);
    float* shift   = (float*)alloc(512);
    unsigned short* WpT = (unsigned short*)alloc(128 * 128 * 2);
    float* Svec    = (float*)alloc(512);
    // lnsum (2 floats) immediately followed by lnpart (pool1 indexes lnpart as lnsum+2)
    float* lnsum   = (float*)alloc(8 + (size_t)AGG_BLOCKS * 2 * 4);
    float* lnpart  = lnsum + 2;
    float* gsum    = (float*)alloc((size_t)NG * F * 4);

    if (used > ws_size) {  // defensive: clean fail instead of wild writes
        hipMemsetAsync(d_out, 0, (size_t)out_size * 4, stream);
        return;
    }

    hipMemsetAsync(bcur, 0, NBK * 4, stream);

    int rpb = (NN + BN_BLOCKS - 1) / BN_BLOCKS;  // 98
    bn_bucket_k<<<BN_BLOCKS + P1_BLOCKS, 256, 0, stream>>>(x, bnpart, NN, rpb, ei, bcur, bbuf);
    finalize_both_k<<<130, 256, 0, stream>>>(bnpart, bnw, bnb, scale, shift, NN,
                                             bcur, bbase, offs, gsum, lnsum);
    prep_hist_k<<<448, 256, 0, stream>>>(W1, scale, shift, WpT, Svec,
                                         bbuf, bcur, bbase, offs, dinv);
    scatter_gemm_k<<<NBK + GEMM_BLOCKS, 256, 0, stream>>>(bbuf, bcur, offs, srow,
                                                          x, WpT, Svec, dinv, hf, NN);
    agg_k<<<AGG_BLOCKS, 256, 0, stream>>>((const uint4*)hf, srow, offs, dinv,
                                          cbias, (uint4*)h2p, lnpart, NN);
    pool1_k<<<(NN + 255) / 256, 256, 0, stream>>>(h2p, batch, gsum, lnsum, NN);
    pool2_k<<<NG, 128, 0, stream>>>(gsum, batch, lnsum, lnw, lnb, linW, linb, out, NN);
}